// Round 1
// baseline (1473.899 us; speedup 1.0000x reference)
//
#include <hip/hip_runtime.h>
#include <math.h>

#define DD 64
#define HIDN 32
#define NH 3
#define SMAX 512   // max atoms per segment on the fast path (mean 40, max ~70 expected)

// ---------------------------------------------------------------------------
// Kernel 1: segment offsets. seg_start[g] = first index i with owner[i] >= g
// (lower_bound). owner is sorted. Handles empty segments via gap fill.
// ---------------------------------------------------------------------------
__global__ void seg_offsets_k(const int* __restrict__ owner, int N, int G,
                              int* __restrict__ seg_start) {
    int i = blockIdx.x * blockDim.x + threadIdx.x;
    if (i >= N) return;
    int cur  = owner[i];
    int prev = (i == 0) ? -1 : owner[i - 1];
    for (int g = prev + 1; g <= cur; ++g) seg_start[g] = i;
    if (i == N - 1) {
        for (int g = cur + 1; g <= G; ++g) seg_start[g] = N;
    }
}

// ---------------------------------------------------------------------------
// Per-atom MLP: scores = silu(x @ w1 + b1) @ w2 + b2   (fp32 throughout)
// hid[32] accumulators = 32 independent FMA chains (issue-bound, not
// latency-bound). w1/w2/b1/b2 addresses are lane-uniform -> scalar loads.
// ---------------------------------------------------------------------------
__device__ __forceinline__ void mlp_scores(const float* __restrict__ fr,
                                           const float* __restrict__ w1,
                                           const float* __restrict__ b1,
                                           const float* __restrict__ w2,
                                           const float* __restrict__ b2,
                                           float& s0, float& s1, float& s2) {
    float hid[HIDN];
#pragma unroll
    for (int j = 0; j < HIDN; ++j) hid[j] = b1[j];

    const float4* fr4 = (const float4*)fr;
    for (int q = 0; q < DD / 4; ++q) {          // 16 iterations, 128 FMA each
        float4 f = fr4[q];
        const float* w1r = w1 + (q * 4) * HIDN;
#pragma unroll
        for (int j = 0; j < HIDN; ++j) {
            hid[j] += f.x * w1r[j];
            hid[j] += f.y * w1r[HIDN + j];
            hid[j] += f.z * w1r[2 * HIDN + j];
            hid[j] += f.w * w1r[3 * HIDN + j];
        }
    }
    s0 = b2[0]; s1 = b2[1]; s2 = b2[2];
#pragma unroll
    for (int j = 0; j < HIDN; ++j) {
        float v = hid[j];
        v = v * __builtin_amdgcn_rcpf(1.0f + __expf(-v));   // silu
        s0 += v * w2[j * NH + 0];
        s1 += v * w2[j * NH + 1];
        s2 += v * w2[j * NH + 2];
    }
}

__device__ __forceinline__ float wave_max(float v) {
#pragma unroll
    for (int m = 32; m >= 1; m >>= 1) v = fmaxf(v, __shfl_xor(v, m, 64));
    return v;
}
__device__ __forceinline__ float wave_sum(float v) {
#pragma unroll
    for (int m = 32; m >= 1; m >>= 1) v += __shfl_xor(v, m, 64);
    return v;
}

// ---------------------------------------------------------------------------
// Cold fallback for segments > SMAX: 3 sweeps with score recomputation,
// chunked 64 atoms at a time through LDS. Never expected to run here, but
// keeps the kernel correct for arbitrary segment sizes.
// ---------------------------------------------------------------------------
__device__ __attribute__((noinline)) void big_segment_path(
    const float* __restrict__ feas, const float* __restrict__ w1,
    const float* __restrict__ b1, const float* __restrict__ w2,
    const float* __restrict__ b2, float* __restrict__ sc,
    int lo, int hi, int lane, float* __restrict__ outg) {
    float m0 = -INFINITY, m1 = -INFINITY, m2 = -INFINITY;
    for (int base = lo; base < hi; base += 64) {
        int a = base + lane;
        if (a < hi) {
            float s0, s1, s2;
            mlp_scores(feas + (size_t)a * DD, w1, b1, w2, b2, s0, s1, s2);
            m0 = fmaxf(m0, s0); m1 = fmaxf(m1, s1); m2 = fmaxf(m2, s2);
        }
    }
    m0 = wave_max(m0); m1 = wave_max(m1); m2 = wave_max(m2);
    float d0 = 0.f, d1 = 0.f, d2 = 0.f;
    for (int base = lo; base < hi; base += 64) {
        int a = base + lane;
        if (a < hi) {
            float s0, s1, s2;
            mlp_scores(feas + (size_t)a * DD, w1, b1, w2, b2, s0, s1, s2);
            d0 += __expf(s0 - m0); d1 += __expf(s1 - m1); d2 += __expf(s2 - m2);
        }
    }
    d0 = wave_sum(d0); d1 = wave_sum(d1); d2 = wave_sum(d2);
    float rd0 = __builtin_amdgcn_rcpf(d0);
    float rd1 = __builtin_amdgcn_rcpf(d1);
    float rd2 = __builtin_amdgcn_rcpf(d2);
    float a0 = 0.f, a1 = 0.f, a2 = 0.f;
    for (int base = lo; base < hi; base += 64) {
        int a = base + lane;
        int cnt = min(64, hi - base);
        __syncthreads();
        if (a < hi) {
            float s0, s1, s2;
            mlp_scores(feas + (size_t)a * DD, w1, b1, w2, b2, s0, s1, s2);
            sc[lane * 3 + 0] = __expf(s0 - m0);
            sc[lane * 3 + 1] = __expf(s1 - m1);
            sc[lane * 3 + 2] = __expf(s2 - m2);
        }
        __syncthreads();
        for (int i = 0; i < cnt; ++i) {
            float f = feas[(size_t)(base + i) * DD + lane];
            a0 += f * sc[i * 3 + 0];
            a1 += f * sc[i * 3 + 1];
            a2 += f * sc[i * 3 + 2];
        }
    }
    outg[lane * 3 + 0] = a0 * rd0;
    outg[lane * 3 + 1] = a1 * rd1;
    outg[lane * 3 + 2] = a2 * rd2;
}

// ---------------------------------------------------------------------------
// Kernel 2: one wave (64 threads) per segment.
//   Phase 1: thread-per-atom score MLP -> LDS
//   Phase 2: per-head segment softmax (shfl reductions)
//   Phase 3: lane=d weighted pooling, coalesced 256B feature re-reads
//            (L1/L2/L3-served: same addresses read by this wave moments ago)
// ---------------------------------------------------------------------------
__global__ void __launch_bounds__(64) seg_attn_pool_k(
    const float* __restrict__ feas, const float* __restrict__ w1,
    const float* __restrict__ b1, const float* __restrict__ w2,
    const float* __restrict__ b2, const int* __restrict__ seg_start,
    float* __restrict__ out) {
    __shared__ float sc[SMAX * 3];   // 6 KB: scores -> exp weights
    const int g = blockIdx.x;
    const int lane = threadIdx.x;
    const int lo = seg_start[g];
    const int hi = seg_start[g + 1];
    const int seg = hi - lo;
    float* outg = out + (size_t)g * (DD * NH);

    if (seg <= 0) {   // empty segment: reference segment_sum gives zeros
        outg[lane] = 0.f; outg[lane + 64] = 0.f; outg[lane + 128] = 0.f;
        return;
    }
    if (seg > SMAX) {
        big_segment_path(feas, w1, b1, w2, b2, sc, lo, hi, lane, outg);
        return;
    }

    // ---- Phase 1: scores -> LDS (stride-3 indexing: banks coprime, no conflicts)
    for (int base = 0; base < seg; base += 64) {
        int i = base + lane;
        if (i < seg) {
            float s0, s1, s2;
            mlp_scores(feas + (size_t)(lo + i) * DD, w1, b1, w2, b2, s0, s1, s2);
            sc[i * 3 + 0] = s0; sc[i * 3 + 1] = s1; sc[i * 3 + 2] = s2;
        }
    }
    __syncthreads();

    // ---- Phase 2: segment softmax per head
    float m0 = -INFINITY, m1 = -INFINITY, m2 = -INFINITY;
    for (int i = lane; i < seg; i += 64) {
        m0 = fmaxf(m0, sc[i * 3 + 0]);
        m1 = fmaxf(m1, sc[i * 3 + 1]);
        m2 = fmaxf(m2, sc[i * 3 + 2]);
    }
    m0 = wave_max(m0); m1 = wave_max(m1); m2 = wave_max(m2);
    float d0 = 0.f, d1 = 0.f, d2 = 0.f;
    for (int i = lane; i < seg; i += 64) {
        float e0 = __expf(sc[i * 3 + 0] - m0);
        float e1 = __expf(sc[i * 3 + 1] - m1);
        float e2 = __expf(sc[i * 3 + 2] - m2);
        sc[i * 3 + 0] = e0; sc[i * 3 + 1] = e1; sc[i * 3 + 2] = e2;
        d0 += e0; d1 += e1; d2 += e2;
    }
    __syncthreads();
    d0 = wave_sum(d0); d1 = wave_sum(d1); d2 = wave_sum(d2);
    const float rd0 = __builtin_amdgcn_rcpf(d0);
    const float rd1 = __builtin_amdgcn_rcpf(d1);
    const float rd2 = __builtin_amdgcn_rcpf(d2);

    // ---- Phase 3: weighted pooling, lane = feature dim d
    float a0 = 0.f, a1 = 0.f, a2 = 0.f;
    const float* fbase = feas + (size_t)lo * DD + lane;
    for (int i = 0; i < seg; ++i) {
        float f = fbase[(size_t)i * DD];        // 64 lanes x 4B = 256B coalesced
        a0 += f * sc[i * 3 + 0];                // LDS broadcasts (free)
        a1 += f * sc[i * 3 + 1];
        a2 += f * sc[i * 3 + 2];
    }
    // out[g, d, h] with head fastest: 12B/lane, contiguous 768B per wave
    outg[lane * 3 + 0] = a0 * rd0;
    outg[lane * 3 + 1] = a1 * rd1;
    outg[lane * 3 + 2] = a2 * rd2;
}

extern "C" void kernel_launch(void* const* d_in, const int* in_sizes, int n_in,
                              void* d_out, int out_size, void* d_ws, size_t ws_size,
                              hipStream_t stream) {
    const float* feas  = (const float*)d_in[0];
    const float* w1    = (const float*)d_in[1];
    const float* b1    = (const float*)d_in[2];
    const float* w2    = (const float*)d_in[3];
    const float* b2    = (const float*)d_in[4];
    const int*   owner = (const int*)d_in[5];
    // d_in[6] = num_segments (device scalar); derive G on host from out_size.
    const int N = in_sizes[5];
    const int G = out_size / (DD * NH);

    int* seg_start = (int*)d_ws;                // (G+1) ints ~ 200 KB
    float* out = (float*)d_out;

    seg_offsets_k<<<(N + 255) / 256, 256, 0, stream>>>(owner, N, G, seg_start);
    seg_attn_pool_k<<<G, 64, 0, stream>>>(feas, w1, b1, w2, b2, seg_start, out);
}